// Round 2
// baseline (548.919 us; speedup 1.0000x reference)
//
#include <hip/hip_runtime.h>
#include <cstdint>
#include <cstddef>

// ---------------------------------------------------------------------------
// GAT (3x single-head GATConv + PReLU, final linear) on MI355X, fp32.
//   - CSR (dst-bucketed) edge index built once per call, reused by 3 layers.
//   - GEMM: 64x128 block tile, 4x8 micro-tile, VALU fp32 (no fp32 MFMA on
//     CDNA4). es/ed attention dots fused into the epilogue; emb[x] gather
//     fused into layer-1 A-tile load via rowidx.
//   - Aggregation: 1 wave per dst node, atomic-free; fast path (deg<=64)
//     does softmax entirely in registers and broadcasts per-edge (src, w)
//     via shfl, so the serial loop has a single global float2 gather.
// ---------------------------------------------------------------------------

#define NEG_SLOPE 0.2f

__global__ void deg_init_kernel(int* __restrict__ deg, int N) {
    int i = blockIdx.x * blockDim.x + threadIdx.x;
    if (i < N) deg[i] = 1;  // self-loop
}

__global__ void hist_kernel(const int* __restrict__ ei, int* __restrict__ deg, int E) {
    int e = blockIdx.x * blockDim.x + threadIdx.x;
    if (e < E) atomicAdd(&deg[ei[E + e]], 1);  // dst = ei[1][e]
}

// 3-phase exclusive scan of deg[N] -> off[N] (+ block sums). 1024 elems/block.
__global__ void scan1_kernel(const int* __restrict__ deg, int* __restrict__ off,
                             int* __restrict__ bsum, int N) {
    __shared__ int lds[256];
    int base = blockIdx.x * 1024;
    int t = threadIdx.x;
    int v[4]; int s = 0;
#pragma unroll
    for (int j = 0; j < 4; j++) {
        int idx = base + t * 4 + j;
        v[j] = (idx < N) ? deg[idx] : 0;
        s += v[j];
    }
    lds[t] = s;
    __syncthreads();
    for (int o = 1; o < 256; o <<= 1) {
        int add = (t >= o) ? lds[t - o] : 0;
        __syncthreads();
        lds[t] += add;
        __syncthreads();
    }
    int run = lds[t] - s;  // exclusive prefix of this thread within block
    if (t == 255) bsum[blockIdx.x] = lds[255];
#pragma unroll
    for (int j = 0; j < 4; j++) {
        int idx = base + t * 4 + j;
        if (idx < N) off[idx] = run;
        run += v[j];
    }
}

__global__ void scan2_kernel(int* __restrict__ bsum, int nblk) {
    __shared__ int lds[256];
    int t = threadIdx.x;
    int v = (t < nblk) ? bsum[t] : 0;
    lds[t] = v;
    __syncthreads();
    for (int o = 1; o < 256; o <<= 1) {
        int add = (t >= o) ? lds[t - o] : 0;
        __syncthreads();
        lds[t] += add;
        __syncthreads();
    }
    if (t < nblk) bsum[t] = lds[t] - v;  // exclusive
}

__global__ void scan3_kernel(int* __restrict__ off, int* __restrict__ cursor,
                             const int* __restrict__ bsum, int N, int E) {
    int base = blockIdx.x * 1024;
    int t = threadIdx.x;
    int add = bsum[blockIdx.x];
#pragma unroll
    for (int j = 0; j < 4; j++) {
        int idx = base + t * 4 + j;
        if (idx < N) {
            int v = off[idx] + add;
            off[idx] = v;
            cursor[idx] = v;
        }
    }
    if (blockIdx.x == 0 && t == 0) off[N] = E + N;
}

// Scatter edges (and self-loops) into dst-sorted src list.
__global__ void fill_kernel(const int* __restrict__ ei, int* __restrict__ cursor,
                            int* __restrict__ srcs, int E, int N) {
    int t = blockIdx.x * blockDim.x + threadIdx.x;
    if (t < E) {
        int s = ei[t];
        int d = ei[E + t];
        int pos = atomicAdd(&cursor[d], 1);
        srcs[pos] = s;
    } else if (t < E + N) {
        int i = t - E;
        int pos = atomicAdd(&cursor[i], 1);
        srcs[pos] = i;
    }
}

// C[M,128] = A'[M,128] @ W[128,128] (+bias), A'[r] = A[rowidx ? rowidx[r] : r].
// Optional fused epilogue: es[r] = C[r,:].avs ; ed[r] = C[r,:].avd
// Block: 256 thr -> 64 rows x 128 cols; thread micro-tile 4 rows x 8 cols.
__global__ __launch_bounds__(256) void gemm128_kernel(
        const float* __restrict__ A, const int* __restrict__ rowidx,
        const float* __restrict__ W, const float* __restrict__ bias,
        const float* __restrict__ avs, const float* __restrict__ avd,
        float* __restrict__ C, float* __restrict__ es, float* __restrict__ ed,
        int M) {
    __shared__ float As[64][36];   // stride 36: 16B-aligned rows, 2-way max conflict
    __shared__ float Bs[32][128];
    int tid = threadIdx.x;
    int row0 = blockIdx.x * 64;
    int ry = tid >> 4;   // 0..15 -> rows ry*4..+3
    int cx = tid & 15;   // 0..15 -> cols cx*8..+7
    float acc[4][8];
#pragma unroll
    for (int i = 0; i < 4; i++)
#pragma unroll
        for (int j = 0; j < 8; j++) acc[i][j] = 0.f;

    for (int k0 = 0; k0 < 128; k0 += 32) {
        if (k0) __syncthreads();
        // A tile: 64 rows x 32 k = 512 float4, 2 per thread
#pragma unroll
        for (int i = 0; i < 2; i++) {
            int f = tid + i * 256;
            int r = f >> 3, c4 = f & 7;
            int gr = row0 + r;
            float4 v = make_float4(0.f, 0.f, 0.f, 0.f);
            if (gr < M) {
                int ar = rowidx ? rowidx[gr] : gr;
                v = ((const float4*)(A + (size_t)ar * 128 + k0))[c4];
            }
            *(float4*)&As[r][c4 * 4] = v;
        }
        // B tile: 32 k x 128 cols = 1024 float4, 4 per thread
#pragma unroll
        for (int i = 0; i < 4; i++) {
            int f = tid + i * 256;
            int kk = f >> 5, c4 = f & 31;
            ((float4*)&Bs[kk][0])[c4] = ((const float4*)(W + (size_t)(k0 + kk) * 128))[c4];
        }
        __syncthreads();
#pragma unroll
        for (int k = 0; k < 32; k++) {
            float a0 = As[ry * 4 + 0][k];
            float a1 = As[ry * 4 + 1][k];
            float a2 = As[ry * 4 + 2][k];
            float a3 = As[ry * 4 + 3][k];
            float4 b0 = ((float4*)&Bs[k][0])[cx * 2];
            float4 b1 = ((float4*)&Bs[k][0])[cx * 2 + 1];
            float bv[8] = {b0.x, b0.y, b0.z, b0.w, b1.x, b1.y, b1.z, b1.w};
#pragma unroll
            for (int j = 0; j < 8; j++) {
                acc[0][j] += a0 * bv[j];
                acc[1][j] += a1 * bv[j];
                acc[2][j] += a2 * bv[j];
                acc[3][j] += a3 * bv[j];
            }
        }
    }
    // store C (+bias)
    float bv[8];
#pragma unroll
    for (int j = 0; j < 8; j++) bv[j] = bias ? bias[cx * 8 + j] : 0.f;
#pragma unroll
    for (int rr = 0; rr < 4; rr++) {
        int r = row0 + ry * 4 + rr;
        if (r >= M) continue;
        float* crow = C + (size_t)r * 128 + cx * 8;
        ((float4*)crow)[0] = make_float4(acc[rr][0] + bv[0], acc[rr][1] + bv[1],
                                         acc[rr][2] + bv[2], acc[rr][3] + bv[3]);
        ((float4*)crow)[1] = make_float4(acc[rr][4] + bv[4], acc[rr][5] + bv[5],
                                         acc[rr][6] + bv[6], acc[rr][7] + bv[7]);
    }
    // fused attention dots: es[r] = g[r,:].avs, ed[r] = g[r,:].avd
    if (es) {
        float vs[8], vd[8];
#pragma unroll
        for (int j = 0; j < 8; j++) { vs[j] = avs[cx * 8 + j]; vd[j] = avd[cx * 8 + j]; }
#pragma unroll
        for (int rr = 0; rr < 4; rr++) {
            float ps = 0.f, pd = 0.f;
#pragma unroll
            for (int j = 0; j < 8; j++) {
                ps += acc[rr][j] * vs[j];
                pd += acc[rr][j] * vd[j];
            }
            // reduce across the 16 cx lanes (lane = (ry&3)*16 + cx)
#pragma unroll
            for (int o = 8; o; o >>= 1) {
                ps += __shfl_xor(ps, o);
                pd += __shfl_xor(pd, o);
            }
            int r = row0 + ry * 4 + rr;
            if (cx == 0 && r < M) { es[r] = ps; ed[r] = pd; }
        }
    }
}

// One wave per dst node: segment softmax + weighted aggregation + bias + PReLU.
__global__ void aggregate_kernel(const float* __restrict__ g, const float* __restrict__ es,
                                 const float* __restrict__ ed, const int* __restrict__ off,
                                 const int* __restrict__ srcs, const float* __restrict__ b,
                                 const float* __restrict__ p, float* __restrict__ hout, int N) {
    int gt = blockIdx.x * blockDim.x + threadIdx.x;
    int i = gt >> 6, lane = gt & 63;
    if (i >= N) return;
    int s0 = off[i], s1 = off[i + 1];
    int cnt = s1 - s0;
    float edi = ed[i];
    float acc0 = 0.f, acc1 = 0.f, z = 0.f;
    if (cnt <= 64) {
        // fast path: one edge per lane, softmax fully in registers
        int sj = 0;
        float e = -3.0e38f;
        if (lane < cnt) {
            sj = srcs[s0 + lane];
            float t = es[sj] + edi;
            e = (t >= 0.f) ? t : NEG_SLOPE * t;
        }
        float m = e;
#pragma unroll
        for (int o = 32; o; o >>= 1) m = fmaxf(m, __shfl_xor(m, o));
        float w = (lane < cnt) ? __expf(e - m) : 0.f;
        z = w;
#pragma unroll
        for (int o = 32; o; o >>= 1) z += __shfl_xor(z, o);
        for (int j = 0; j < cnt; ++j) {
            int s = __shfl(sj, j);
            float wj = __shfl(w, j);
            float2 gv = *(const float2*)(g + (size_t)s * 128 + lane * 2);
            acc0 += wj * gv.x;
            acc1 += wj * gv.y;
        }
    } else {
        // generic path (rare: deg > 64)
        float m = -3.0e38f;
        for (int j = s0 + lane; j < s1; j += 64) {
            float t = es[srcs[j]] + edi;
            t = (t >= 0.f) ? t : NEG_SLOPE * t;
            m = fmaxf(m, t);
        }
#pragma unroll
        for (int o = 32; o; o >>= 1) m = fmaxf(m, __shfl_xor(m, o));
        for (int j = s0; j < s1; ++j) {
            int s = srcs[j];
            float t = es[s] + edi;
            t = (t >= 0.f) ? t : NEG_SLOPE * t;
            float w = __expf(t - m);
            z += w;
            float2 gv = *(const float2*)(g + (size_t)s * 128 + lane * 2);
            acc0 += w * gv.x;
            acc1 += w * gv.y;
        }
    }
    float pv = p[0];
    float inv = 1.f / z;
    float2 bb = *(const float2*)(b + lane * 2);
    float o0 = acc0 * inv + bb.x;
    float o1 = acc1 * inv + bb.y;
    o0 = (o0 >= 0.f) ? o0 : pv * o0;
    o1 = (o1 >= 0.f) ? o1 : pv * o1;
    *(float2*)(hout + (size_t)i * 128 + lane * 2) = make_float2(o0, o1);
}

extern "C" void kernel_launch(void* const* d_in, const int* in_sizes, int n_in,
                              void* d_out, int out_size, void* d_ws, size_t ws_size,
                              hipStream_t stream) {
    const int*   x   = (const int*)d_in[0];
    const int*   ei  = (const int*)d_in[1];
    // d_in[2] = edge_weight: unused by the reference
    const float* emb = (const float*)d_in[3];
    const float* W1  = (const float*)d_in[4];
    const float* as1 = (const float*)d_in[5];
    const float* ad1 = (const float*)d_in[6];
    const float* b1  = (const float*)d_in[7];
    const float* p1  = (const float*)d_in[8];
    const float* W2  = (const float*)d_in[9];
    const float* as2 = (const float*)d_in[10];
    const float* ad2 = (const float*)d_in[11];
    const float* b2  = (const float*)d_in[12];
    const float* p2  = (const float*)d_in[13];
    const float* W3  = (const float*)d_in[14];
    const float* as3 = (const float*)d_in[15];
    const float* ad3 = (const float*)d_in[16];
    const float* b3  = (const float*)d_in[17];
    const float* p3  = (const float*)d_in[18];
    const float* Wo  = (const float*)d_in[19];
    const float* bo  = (const float*)d_in[20];

    const int N = in_sizes[0];
    const int E = in_sizes[2];  // edge_weight length

    // workspace carve (256B aligned)
    char* wp = (char*)d_ws;
    auto carve = [&](size_t bytes) {
        char* r = wp;
        wp += (bytes + 255) & ~(size_t)255;
        return r;
    };
    float* h0     = (float*)carve((size_t)N * 128 * 4);
    float* h1     = (float*)carve((size_t)N * 128 * 4);
    float* g      = (float*)carve((size_t)N * 128 * 4);
    float* es     = (float*)carve((size_t)N * 4);
    float* ed     = (float*)carve((size_t)N * 4);
    int*   deg    = (int*)carve((size_t)N * 4);
    int*   off    = (int*)carve((size_t)(N + 1) * 4);
    int*   cursor = (int*)carve((size_t)N * 4);
    int*   srcs   = (int*)carve((size_t)(E + N) * 4);
    int*   bsum   = (int*)carve(1024 * 4);
    (void)ws_size; (void)n_in;

    // CSR build (once; reused by all 3 layers)
    deg_init_kernel<<<(N + 255) / 256, 256, 0, stream>>>(deg, N);
    hist_kernel<<<(E + 255) / 256, 256, 0, stream>>>(ei, deg, E);
    int nblk = (N + 1023) / 1024;
    scan1_kernel<<<nblk, 256, 0, stream>>>(deg, off, bsum, N);
    scan2_kernel<<<1, 256, 0, stream>>>(bsum, nblk);
    scan3_kernel<<<nblk, 256, 0, stream>>>(off, cursor, bsum, N, E);
    fill_kernel<<<(E + N + 255) / 256, 256, 0, stream>>>(ei, cursor, srcs, E, N);

    int gemm_grid = (N + 63) / 64;
    int wave_grid = (N * 64 + 255) / 256;

    // layer 1: emb[x] -> h1   (gather fused into GEMM A-load via rowidx=x)
    gemm128_kernel<<<gemm_grid, 256, 0, stream>>>(emb, x, W1, nullptr, as1, ad1, g, es, ed, N);
    aggregate_kernel<<<wave_grid, 256, 0, stream>>>(g, es, ed, off, srcs, b1, p1, h1, N);
    // layer 2: h1 -> h0
    gemm128_kernel<<<gemm_grid, 256, 0, stream>>>(h1, nullptr, W2, nullptr, as2, ad2, g, es, ed, N);
    aggregate_kernel<<<wave_grid, 256, 0, stream>>>(g, es, ed, off, srcs, b2, p2, h0, N);
    // layer 3: h0 -> h1
    gemm128_kernel<<<gemm_grid, 256, 0, stream>>>(h0, nullptr, W3, nullptr, as3, ad3, g, es, ed, N);
    aggregate_kernel<<<wave_grid, 256, 0, stream>>>(g, es, ed, off, srcs, b3, p3, h1, N);
    // output projection
    gemm128_kernel<<<gemm_grid, 256, 0, stream>>>(h1, nullptr, Wo, bo, nullptr, nullptr,
                                                  (float*)d_out, nullptr, nullptr, N);
}

// Round 6
// 515.844 us; speedup vs baseline: 1.0641x; 1.0641x over previous
//
#include <hip/hip_runtime.h>
#include <cstdint>
#include <cstddef>

// ---------------------------------------------------------------------------
// GAT (3x single-head GATConv + PReLU, final linear) on MI355X, fp32.
//   - CSR (dst-bucketed) edge index built once per call, reused by 3 layers.
//   - GEMM: 64-row block, W half-tiles in LDS (2-way-bank reads), A streamed
//     from global. es/ed dots fused in epilogue; emb[x] gather via rowidx.
//   - Aggregation: 1 wave per dst node; 2 half-waves x 4-unroll = 8
//     outstanding 512B gathers/wave. ALL gather-loop bounds are wave-uniform:
//     round-4 fail was __shfl under half-diverged loops (ds_bpermute from
//     inactive lanes = undefined). Tail relies on w[lane>=cnt]==0.
// ---------------------------------------------------------------------------

#define NEG_SLOPE 0.2f

__device__ __forceinline__ float leaky(float t) { return t >= 0.f ? t : NEG_SLOPE * t; }

__global__ void deg_init_kernel(int* __restrict__ deg, int N) {
    int i = blockIdx.x * blockDim.x + threadIdx.x;
    if (i < N) deg[i] = 1;  // self-loop
}

__global__ void hist_kernel(const int* __restrict__ ei, int* __restrict__ deg, int E) {
    int e = blockIdx.x * blockDim.x + threadIdx.x;
    if (e < E) atomicAdd(&deg[ei[E + e]], 1);  // dst = ei[1][e]
}

// 3-phase exclusive scan of deg[N] -> off[N] (+ block sums). 1024 elems/block.
__global__ void scan1_kernel(const int* __restrict__ deg, int* __restrict__ off,
                             int* __restrict__ bsum, int N) {
    __shared__ int lds[256];
    int base = blockIdx.x * 1024;
    int t = threadIdx.x;
    int v[4]; int s = 0;
#pragma unroll
    for (int j = 0; j < 4; j++) {
        int idx = base + t * 4 + j;
        v[j] = (idx < N) ? deg[idx] : 0;
        s += v[j];
    }
    lds[t] = s;
    __syncthreads();
    for (int o = 1; o < 256; o <<= 1) {
        int add = (t >= o) ? lds[t - o] : 0;
        __syncthreads();
        lds[t] += add;
        __syncthreads();
    }
    int run = lds[t] - s;
    if (t == 255) bsum[blockIdx.x] = lds[255];
#pragma unroll
    for (int j = 0; j < 4; j++) {
        int idx = base + t * 4 + j;
        if (idx < N) off[idx] = run;
        run += v[j];
    }
}

__global__ void scan2_kernel(int* __restrict__ bsum, int nblk) {
    __shared__ int lds[256];
    int t = threadIdx.x;
    int v = (t < nblk) ? bsum[t] : 0;
    lds[t] = v;
    __syncthreads();
    for (int o = 1; o < 256; o <<= 1) {
        int add = (t >= o) ? lds[t - o] : 0;
        __syncthreads();
        lds[t] += add;
        __syncthreads();
    }
    if (t < nblk) bsum[t] = lds[t] - v;  // exclusive
}

__global__ void scan3_kernel(int* __restrict__ off, int* __restrict__ cursor,
                             const int* __restrict__ bsum, int N, int E) {
    int base = blockIdx.x * 1024;
    int t = threadIdx.x;
    int add = bsum[blockIdx.x];
#pragma unroll
    for (int j = 0; j < 4; j++) {
        int idx = base + t * 4 + j;
        if (idx < N) {
            int v = off[idx] + add;
            off[idx] = v;
            cursor[idx] = v;
        }
    }
    if (blockIdx.x == 0 && t == 0) off[N] = E + N;
}

__global__ void fill_kernel(const int* __restrict__ ei, int* __restrict__ cursor,
                            int* __restrict__ srcs, int E, int N) {
    int t = blockIdx.x * blockDim.x + threadIdx.x;
    if (t < E) {
        int s = ei[t];
        int d = ei[E + t];
        int pos = atomicAdd(&cursor[d], 1);
        srcs[pos] = s;
    } else if (t < E + N) {
        int i = t - E;
        int pos = atomicAdd(&cursor[i], 1);
        srcs[pos] = i;
    }
}

// C[M,128] = A'[M,128] @ W[128,128] (+bias), A'[r] = A[rowidx ? rowidx[r] : r].
// Optional fused epilogue: es[r] = C[r,:].avs ; ed[r] = C[r,:].avd
// 256 thr -> 64 rows; thread (ry,cx) owns rows ry*4..+3, cols {cx*4..+3, 64+cx*4..+3}.
// A streamed from global (float4/row/4k); W half-tile (64x128) staged in LDS.
__global__ __launch_bounds__(256) void gemm128_kernel(
        const float* __restrict__ A, const int* __restrict__ rowidx,
        const float* __restrict__ W, const float* __restrict__ bias,
        const float* __restrict__ avs, const float* __restrict__ avd,
        float* __restrict__ C, float* __restrict__ es, float* __restrict__ ed,
        int M) {
    __shared__ float Bs[64][128];   // row = k, col = n; 16B stride over cx -> 2-way (free)
    int tid = threadIdx.x;
    int row0 = blockIdx.x * 64;
    int ry = tid >> 4;   // 0..15
    int cx = tid & 15;   // 0..15

    const float* arow[4];
#pragma unroll
    for (int rr = 0; rr < 4; rr++) {
        int gr = row0 + ry * 4 + rr;
        int ar = 0;
        if (gr < M) ar = rowidx ? rowidx[gr] : gr;
        arow[rr] = A + (size_t)ar * 128;
    }

    float acc[4][8];
#pragma unroll
    for (int i = 0; i < 4; i++)
#pragma unroll
        for (int j = 0; j < 8; j++) acc[i][j] = 0.f;

    for (int k0 = 0; k0 < 128; k0 += 64) {
        if (k0) __syncthreads();
        // stage W[k0..k0+63][:] : 2048 float4, 8 per thread
#pragma unroll
        for (int i = 0; i < 8; i++) {
            int f = tid + i * 256;
            int kk = f >> 5, c4 = f & 31;
            *(float4*)&Bs[kk][c4 * 4] = ((const float4*)(W + (size_t)(k0 + kk) * 128))[c4];
        }
        __syncthreads();
#pragma unroll 2
        for (int k4 = 0; k4 < 16; k4++) {
            float4 a4[4];
#pragma unroll
            for (int rr = 0; rr < 4; rr++)
                a4[rr] = *(const float4*)(arow[rr] + k0 + k4 * 4);
#pragma unroll
            for (int kk = 0; kk < 4; kk++) {
                float4 b0 = *(const float4*)&Bs[k4 * 4 + kk][cx * 4];
                float4 b1 = *(const float4*)&Bs[k4 * 4 + kk][64 + cx * 4];
#pragma unroll
                for (int rr = 0; rr < 4; rr++) {
                    float a = (kk == 0) ? a4[rr].x : (kk == 1) ? a4[rr].y
                              : (kk == 2) ? a4[rr].z : a4[rr].w;
                    acc[rr][0] += a * b0.x; acc[rr][1] += a * b0.y;
                    acc[rr][2] += a * b0.z; acc[rr][3] += a * b0.w;
                    acc[rr][4] += a * b1.x; acc[rr][5] += a * b1.y;
                    acc[rr][6] += a * b1.z; acc[rr][7] += a * b1.w;
                }
            }
        }
    }
    // store C (+bias): cols cx*4..+3 and 64+cx*4..+3
    float bv[8];
#pragma unroll
    for (int j = 0; j < 4; j++) {
        bv[j]     = bias ? bias[cx * 4 + j] : 0.f;
        bv[4 + j] = bias ? bias[64 + cx * 4 + j] : 0.f;
    }
#pragma unroll
    for (int rr = 0; rr < 4; rr++) {
        int r = row0 + ry * 4 + rr;
        if (r >= M) continue;
        float* crow = C + (size_t)r * 128;
        *(float4*)(crow + cx * 4) = make_float4(acc[rr][0] + bv[0], acc[rr][1] + bv[1],
                                                acc[rr][2] + bv[2], acc[rr][3] + bv[3]);
        *(float4*)(crow + 64 + cx * 4) = make_float4(acc[rr][4] + bv[4], acc[rr][5] + bv[5],
                                                     acc[rr][6] + bv[6], acc[rr][7] + bv[7]);
    }
    // fused attention dots: es[r] = C[r,:].avs, ed[r] = C[r,:].avd
    if (es) {
        float vs[8], vd[8];
#pragma unroll
        for (int j = 0; j < 4; j++) {
            vs[j] = avs[cx * 4 + j];          vd[j] = avd[cx * 4 + j];
            vs[4 + j] = avs[64 + cx * 4 + j]; vd[4 + j] = avd[64 + cx * 4 + j];
        }
#pragma unroll
        for (int rr = 0; rr < 4; rr++) {
            float ps = 0.f, pd = 0.f;
#pragma unroll
            for (int j = 0; j < 8; j++) {
                ps += acc[rr][j] * vs[j];
                pd += acc[rr][j] * vd[j];
            }
#pragma unroll
            for (int o = 8; o; o >>= 1) {   // reduce across the 16 cx lanes
                ps += __shfl_xor(ps, o);
                pd += __shfl_xor(pd, o);
            }
            int r = row0 + ry * 4 + rr;
            if (cx == 0 && r < M) { es[r] = ps; ed[r] = pd; }
        }
    }
}

// One wave per dst node: segment softmax + weighted aggregation + bias + PReLU.
// Half-wave (32 lanes x float4 = 512B) per edge row; pairs of edges per step,
// 4x unroll. All loop bounds wave-uniform so every __shfl runs with the full
// wave active (w[lane>=cnt]==0 masks the half-1 overhang in the tail).
__global__ void aggregate_kernel(const float* __restrict__ g, const float* __restrict__ es,
                                 const float* __restrict__ ed, const int* __restrict__ off,
                                 const int* __restrict__ srcs, const float* __restrict__ b,
                                 const float* __restrict__ p, float* __restrict__ hout, int N) {
    int gt = blockIdx.x * blockDim.x + threadIdx.x;
    int i = gt >> 6, lane = gt & 63;
    if (i >= N) return;
    int s0 = off[i], s1 = off[i + 1];
    int cnt = s1 - s0;
    float edi = ed[i];
    int half = lane >> 5, l32 = lane & 31;
    float4 acc = make_float4(0.f, 0.f, 0.f, 0.f);
    float z = 0.f;
    if (cnt <= 64) {
        // softmax fully in registers: one edge per lane
        int sj = 0;                 // lanes >= cnt keep sj=0 (harmless row 0)
        float e = -3.0e38f;
        if (lane < cnt) {
            sj = srcs[s0 + lane];
            e = leaky(es[sj] + edi);
        }
        float m = e;
#pragma unroll
        for (int o = 32; o; o >>= 1) m = fmaxf(m, __shfl_xor(m, o));
        float w = (lane < cnt) ? __expf(e - m) : 0.f;   // ==0 masks tail overhang
        z = w;
#pragma unroll
        for (int o = 32; o; o >>= 1) z += __shfl_xor(z, o);
        // main: 8 edges per step (4 per half), all indices < cnt <= 64
        int jb = 0;
        for (; jb + 8 <= cnt; jb += 8) {
            int j0 = jb + half, j1 = jb + 2 + half, j2 = jb + 4 + half, j3 = jb + 6 + half;
            int   sa = __shfl(sj, j0), sb = __shfl(sj, j1);
            int   sc = __shfl(sj, j2), sd = __shfl(sj, j3);
            float wa = __shfl(w, j0),  wb = __shfl(w, j1);
            float wc = __shfl(w, j2),  wd = __shfl(w, j3);
            float4 ga = *(const float4*)(g + (size_t)sa * 128 + l32 * 4);
            float4 gb = *(const float4*)(g + (size_t)sb * 128 + l32 * 4);
            float4 gc = *(const float4*)(g + (size_t)sc * 128 + l32 * 4);
            float4 gd = *(const float4*)(g + (size_t)sd * 128 + l32 * 4);
            acc.x += wa * ga.x + wb * gb.x + wc * gc.x + wd * gd.x;
            acc.y += wa * ga.y + wb * gb.y + wc * gc.y + wd * gd.y;
            acc.z += wa * ga.z + wb * gb.z + wc * gc.z + wd * gd.z;
            acc.w += wa * ga.w + wb * gb.w + wc * gc.w + wd * gd.w;
        }
        // tail: 2 edges per step; j = jb+half <= 63 always (jb even, jb < cnt),
        // and for j >= cnt the shfl'd w is 0 -> contributes nothing.
        for (; jb < cnt; jb += 2) {
            int j = jb + half;
            int   sa = __shfl(sj, j);
            float wa = __shfl(w, j);
            float4 ga = *(const float4*)(g + (size_t)sa * 128 + l32 * 4);
            acc.x += wa * ga.x; acc.y += wa * ga.y;
            acc.z += wa * ga.z; acc.w += wa * ga.w;
        }
    } else {
        // generic path (deg > 64, rare) — no shfl inside divergent region
        float m = -3.0e38f;
        for (int jj = s0 + lane; jj < s1; jj += 64)
            m = fmaxf(m, leaky(es[srcs[jj]] + edi));
#pragma unroll
        for (int o = 32; o; o >>= 1) m = fmaxf(m, __shfl_xor(m, o));
        for (int j = s0 + half; j < s1; j += 2) {
            int s = srcs[j];
            float wj = __expf(leaky(es[s] + edi) - m);
            z += wj;
            float4 gv = *(const float4*)(g + (size_t)s * 128 + l32 * 4);
            acc.x += wj * gv.x; acc.y += wj * gv.y;
            acc.z += wj * gv.z; acc.w += wj * gv.w;
        }
        z += __shfl_xor(z, 32);
    }
    // combine the two half-wave partials (same cols l32*4..+3)
    acc.x += __shfl_xor(acc.x, 32);
    acc.y += __shfl_xor(acc.y, 32);
    acc.z += __shfl_xor(acc.z, 32);
    acc.w += __shfl_xor(acc.w, 32);
    if (half == 0) {
        float pv = p[0];
        float inv = 1.f / z;
        float4 bb = *(const float4*)(b + l32 * 4);
        float o0 = acc.x * inv + bb.x;
        float o1 = acc.y * inv + bb.y;
        float o2 = acc.z * inv + bb.z;
        float o3 = acc.w * inv + bb.w;
        o0 = (o0 >= 0.f) ? o0 : pv * o0;
        o1 = (o1 >= 0.f) ? o1 : pv * o1;
        o2 = (o2 >= 0.f) ? o2 : pv * o2;
        o3 = (o3 >= 0.f) ? o3 : pv * o3;
        *(float4*)(hout + (size_t)i * 128 + l32 * 4) = make_float4(o0, o1, o2, o3);
    }
}

extern "C" void kernel_launch(void* const* d_in, const int* in_sizes, int n_in,
                              void* d_out, int out_size, void* d_ws, size_t ws_size,
                              hipStream_t stream) {
    const int*   x   = (const int*)d_in[0];
    const int*   ei  = (const int*)d_in[1];
    // d_in[2] = edge_weight: unused by the reference
    const float* emb = (const float*)d_in[3];
    const float* W1  = (const float*)d_in[4];
    const float* as1 = (const float*)d_in[5];
    const float* ad1 = (const float*)d_in[6];
    const float* b1  = (const float*)d_in[7];
    const float* p1  = (const float*)d_in[8];
    const float* W2  = (const float*)d_in[9];
    const float* as2 = (const float*)d_in[10];
    const float* ad2 = (const float*)d_in[11];
    const float* b2  = (const float*)d_in[12];
    const float* p2  = (const float*)d_in[13];
    const float* W3  = (const float*)d_in[14];
    const float* as3 = (const float*)d_in[15];
    const float* ad3 = (const float*)d_in[16];
    const float* b3  = (const float*)d_in[17];
    const float* p3  = (const float*)d_in[18];
    const float* Wo  = (const float*)d_in[19];
    const float* bo  = (const float*)d_in[20];

    const int N = in_sizes[0];
    const int E = in_sizes[2];  // edge_weight length

    // workspace carve (256B aligned)
    char* wp = (char*)d_ws;
    auto carve = [&](size_t bytes) {
        char* r = wp;
        wp += (bytes + 255) & ~(size_t)255;
        return r;
    };
    float* h0     = (float*)carve((size_t)N * 128 * 4);
    float* h1     = (float*)carve((size_t)N * 128 * 4);
    float* g      = (float*)carve((size_t)N * 128 * 4);
    float* es     = (float*)carve((size_t)N * 4);
    float* ed     = (float*)carve((size_t)N * 4);
    int*   deg    = (int*)carve((size_t)N * 4);
    int*   off    = (int*)carve((size_t)(N + 1) * 4);
    int*   cursor = (int*)carve((size_t)N * 4);
    int*   srcs   = (int*)carve((size_t)(E + N) * 4);
    int*   bsum   = (int*)carve(1024 * 4);
    (void)ws_size; (void)n_in;

    // CSR build (once; reused by all 3 layers)
    deg_init_kernel<<<(N + 255) / 256, 256, 0, stream>>>(deg, N);
    hist_kernel<<<(E + 255) / 256, 256, 0, stream>>>(ei, deg, E);
    int nblk = (N + 1023) / 1024;
    scan1_kernel<<<nblk, 256, 0, stream>>>(deg, off, bsum, N);
    scan2_kernel<<<1, 256, 0, stream>>>(bsum, nblk);
    scan3_kernel<<<nblk, 256, 0, stream>>>(off, cursor, bsum, N, E);
    fill_kernel<<<(E + N + 255) / 256, 256, 0, stream>>>(ei, cursor, srcs, E, N);

    int gemm_grid = (N + 63) / 64;
    int wave_grid = (N * 64 + 255) / 256;

    // layer 1: emb[x] -> h1   (gather fused into GEMM A-load via rowidx=x)
    gemm128_kernel<<<gemm_grid, 256, 0, stream>>>(emb, x, W1, nullptr, as1, ad1, g, es, ed, N);
    aggregate_kernel<<<wave_grid, 256, 0, stream>>>(g, es, ed, off, srcs, b1, p1, h1, N);
    // layer 2: h1 -> h0
    gemm128_kernel<<<gemm_grid, 256, 0, stream>>>(h1, nullptr, W2, nullptr, as2, ad2, g, es, ed, N);
    aggregate_kernel<<<wave_grid, 256, 0, stream>>>(g, es, ed, off, srcs, b2, p2, h0, N);
    // layer 3: h0 -> h1
    gemm128_kernel<<<gemm_grid, 256, 0, stream>>>(h0, nullptr, W3, nullptr, as3, ad3, g, es, ed, N);
    aggregate_kernel<<<wave_grid, 256, 0, stream>>>(g, es, ed, off, srcs, b3, p3, h1, N);
    // output projection
    gemm128_kernel<<<gemm_grid, 256, 0, stream>>>(h1, nullptr, Wo, bo, nullptr, nullptr,
                                                  (float*)d_out, nullptr, nullptr, N);
}

// Round 12
// 506.275 us; speedup vs baseline: 1.0842x; 1.0189x over previous
//
#include <hip/hip_runtime.h>
#include <cstdint>
#include <cstddef>

// ---------------------------------------------------------------------------
// GAT (3x single-head GATConv + PReLU, final linear) on MI355X, fp32.
//   - CSR (dst-bucketed) edge index built once per call, reused by 3 layers.
//   - GEMM: 64x128 block; A tile staged in LDS [64][68] (pad 68: scalar row
//     reads = 2-way bank alias, free) -- removes the 16x redundant global/L1
//     A-reads of the round-6 version. W 64x128 half-tile in LDS. es/ed dots
//     fused in epilogue; emb[x] gather via rowidx.
//   - Aggregation: unchanged from round 6 (60us, 3.6TB/s, FETCH=g x 8 XCDs =
//     structural replication; saturating, likely pattern-ceiling).
// ---------------------------------------------------------------------------

#define NEG_SLOPE 0.2f

__device__ __forceinline__ float leaky(float t) { return t >= 0.f ? t : NEG_SLOPE * t; }

__global__ void deg_init_kernel(int* __restrict__ deg, int N) {
    int i = blockIdx.x * blockDim.x + threadIdx.x;
    if (i < N) deg[i] = 1;  // self-loop
}

__global__ void hist_kernel(const int* __restrict__ ei, int* __restrict__ deg, int E) {
    int e = blockIdx.x * blockDim.x + threadIdx.x;
    if (e < E) atomicAdd(&deg[ei[E + e]], 1);  // dst = ei[1][e]
}

// 3-phase exclusive scan of deg[N] -> off[N] (+ block sums). 1024 elems/block.
__global__ void scan1_kernel(const int* __restrict__ deg, int* __restrict__ off,
                             int* __restrict__ bsum, int N) {
    __shared__ int lds[256];
    int base = blockIdx.x * 1024;
    int t = threadIdx.x;
    int v[4]; int s = 0;
#pragma unroll
    for (int j = 0; j < 4; j++) {
        int idx = base + t * 4 + j;
        v[j] = (idx < N) ? deg[idx] : 0;
        s += v[j];
    }
    lds[t] = s;
    __syncthreads();
    for (int o = 1; o < 256; o <<= 1) {
        int add = (t >= o) ? lds[t - o] : 0;
        __syncthreads();
        lds[t] += add;
        __syncthreads();
    }
    int run = lds[t] - s;
    if (t == 255) bsum[blockIdx.x] = lds[255];
#pragma unroll
    for (int j = 0; j < 4; j++) {
        int idx = base + t * 4 + j;
        if (idx < N) off[idx] = run;
        run += v[j];
    }
}

__global__ void scan2_kernel(int* __restrict__ bsum, int nblk) {
    __shared__ int lds[256];
    int t = threadIdx.x;
    int v = (t < nblk) ? bsum[t] : 0;
    lds[t] = v;
    __syncthreads();
    for (int o = 1; o < 256; o <<= 1) {
        int add = (t >= o) ? lds[t - o] : 0;
        __syncthreads();
        lds[t] += add;
        __syncthreads();
    }
    if (t < nblk) bsum[t] = lds[t] - v;  // exclusive
}

__global__ void scan3_kernel(int* __restrict__ off, int* __restrict__ cursor,
                             const int* __restrict__ bsum, int N, int E) {
    int base = blockIdx.x * 1024;
    int t = threadIdx.x;
    int add = bsum[blockIdx.x];
#pragma unroll
    for (int j = 0; j < 4; j++) {
        int idx = base + t * 4 + j;
        if (idx < N) {
            int v = off[idx] + add;
            off[idx] = v;
            cursor[idx] = v;
        }
    }
    if (blockIdx.x == 0 && t == 0) off[N] = E + N;
}

__global__ void fill_kernel(const int* __restrict__ ei, int* __restrict__ cursor,
                            int* __restrict__ srcs, int E, int N) {
    int t = blockIdx.x * blockDim.x + threadIdx.x;
    if (t < E) {
        int s = ei[t];
        int d = ei[E + t];
        int pos = atomicAdd(&cursor[d], 1);
        srcs[pos] = s;
    } else if (t < E + N) {
        int i = t - E;
        int pos = atomicAdd(&cursor[i], 1);
        srcs[pos] = i;
    }
}

// C[M,128] = A'[M,128] @ W[128,128] (+bias), A'[r] = A[rowidx ? rowidx[r] : r].
// Optional fused epilogue: es[r] = C[r,:].avs ; ed[r] = C[r,:].avd
// 256 thr -> 64 rows; thread (ry,cx): rows ry*4..+3, cols {cx*4..+3, 64+cx*4..+3}.
// Both A (64x64, LDS [64][68]) and W (64x128) tiles staged in LDS per k0-half.
__global__ __launch_bounds__(256) void gemm128_kernel(
        const float* __restrict__ A, const int* __restrict__ rowidx,
        const float* __restrict__ W, const float* __restrict__ bias,
        const float* __restrict__ avs, const float* __restrict__ avd,
        float* __restrict__ C, float* __restrict__ es, float* __restrict__ ed,
        int M) {
    __shared__ float As[64][68];    // 64 rows x 64 k, pad->68: row reads 2-way (free)
    __shared__ float Bs[64][128];   // row = k, col = n; 16B stride over cx -> 2-way (free)
    int tid = threadIdx.x;
    int row0 = blockIdx.x * 64;
    int ry = tid >> 4;   // 0..15
    int cx = tid & 15;   // 0..15

    // staging assignment for As: thread stages rows sr (4 float4s along k)
    int sr = tid >> 2;        // 0..63: which row this thread stages
    int sc4 = tid & 3;        // 0..3: float4 group base (stage 4, stride 4)
    int sgr = row0 + sr;
    int sar = 0;
    if (sgr < M) sar = rowidx ? rowidx[sgr] : sgr;
    const float* asrc = A + (size_t)sar * 128;

    float acc[4][8];
#pragma unroll
    for (int i = 0; i < 4; i++)
#pragma unroll
        for (int j = 0; j < 8; j++) acc[i][j] = 0.f;

    for (int k0 = 0; k0 < 128; k0 += 64) {
        if (k0) __syncthreads();
        // stage A[row0..+63][k0..+63]: 64 rows x 16 float4 = 1024, 4/thread
#pragma unroll
        for (int i = 0; i < 4; i++) {
            int c4 = sc4 + i * 4;     // 0..15
            *(float4*)&As[sr][c4 * 4] = ((const float4*)(asrc + k0))[c4];
        }
        // stage W[k0..k0+63][:] : 2048 float4, 8 per thread
#pragma unroll
        for (int i = 0; i < 8; i++) {
            int f = tid + i * 256;
            int kk = f >> 5, c4 = f & 31;
            *(float4*)&Bs[kk][c4 * 4] = ((const float4*)(W + (size_t)(k0 + kk) * 128))[c4];
        }
        __syncthreads();
#pragma unroll 4
        for (int k4 = 0; k4 < 16; k4++) {
            float4 a4[4];
#pragma unroll
            for (int rr = 0; rr < 4; rr++)
                a4[rr] = *(const float4*)&As[ry * 4 + rr][k4 * 4];
#pragma unroll
            for (int kk = 0; kk < 4; kk++) {
                float4 b0 = *(const float4*)&Bs[k4 * 4 + kk][cx * 4];
                float4 b1 = *(const float4*)&Bs[k4 * 4 + kk][64 + cx * 4];
#pragma unroll
                for (int rr = 0; rr < 4; rr++) {
                    float a = (kk == 0) ? a4[rr].x : (kk == 1) ? a4[rr].y
                              : (kk == 2) ? a4[rr].z : a4[rr].w;
                    acc[rr][0] += a * b0.x; acc[rr][1] += a * b0.y;
                    acc[rr][2] += a * b0.z; acc[rr][3] += a * b0.w;
                    acc[rr][4] += a * b1.x; acc[rr][5] += a * b1.y;
                    acc[rr][6] += a * b1.z; acc[rr][7] += a * b1.w;
                }
            }
        }
    }
    // store C (+bias): cols cx*4..+3 and 64+cx*4..+3
    float bv[8];
#pragma unroll
    for (int j = 0; j < 4; j++) {
        bv[j]     = bias ? bias[cx * 4 + j] : 0.f;
        bv[4 + j] = bias ? bias[64 + cx * 4 + j] : 0.f;
    }
#pragma unroll
    for (int rr = 0; rr < 4; rr++) {
        int r = row0 + ry * 4 + rr;
        if (r >= M) continue;
        float* crow = C + (size_t)r * 128;
        *(float4*)(crow + cx * 4) = make_float4(acc[rr][0] + bv[0], acc[rr][1] + bv[1],
                                                acc[rr][2] + bv[2], acc[rr][3] + bv[3]);
        *(float4*)(crow + 64 + cx * 4) = make_float4(acc[rr][4] + bv[4], acc[rr][5] + bv[5],
                                                     acc[rr][6] + bv[6], acc[rr][7] + bv[7]);
    }
    // fused attention dots: es[r] = C[r,:].avs, ed[r] = C[r,:].avd
    if (es) {
        float vs[8], vd[8];
#pragma unroll
        for (int j = 0; j < 4; j++) {
            vs[j] = avs[cx * 4 + j];          vd[j] = avd[cx * 4 + j];
            vs[4 + j] = avs[64 + cx * 4 + j]; vd[4 + j] = avd[64 + cx * 4 + j];
        }
#pragma unroll
        for (int rr = 0; rr < 4; rr++) {
            float ps = 0.f, pd = 0.f;
#pragma unroll
            for (int j = 0; j < 8; j++) {
                ps += acc[rr][j] * vs[j];
                pd += acc[rr][j] * vd[j];
            }
#pragma unroll
            for (int o = 8; o; o >>= 1) {   // reduce across the 16 cx lanes
                ps += __shfl_xor(ps, o);
                pd += __shfl_xor(pd, o);
            }
            int r = row0 + ry * 4 + rr;
            if (cx == 0 && r < M) { es[r] = ps; ed[r] = pd; }
        }
    }
}

// One wave per dst node: segment softmax + weighted aggregation + bias + PReLU.
// Half-wave (32 lanes x float4 = 512B) per edge row; pairs of edges per step,
// 4x unroll. All loop bounds wave-uniform so every __shfl runs with the full
// wave active (w[lane>=cnt]==0 masks the half-1 overhang in the tail).
__global__ void aggregate_kernel(const float* __restrict__ g, const float* __restrict__ es,
                                 const float* __restrict__ ed, const int* __restrict__ off,
                                 const int* __restrict__ srcs, const float* __restrict__ b,
                                 const float* __restrict__ p, float* __restrict__ hout, int N) {
    int gt = blockIdx.x * blockDim.x + threadIdx.x;
    int i = gt >> 6, lane = gt & 63;
    if (i >= N) return;
    int s0 = off[i], s1 = off[i + 1];
    int cnt = s1 - s0;
    float edi = ed[i];
    int half = lane >> 5, l32 = lane & 31;
    float4 acc = make_float4(0.f, 0.f, 0.f, 0.f);
    float z = 0.f;
    if (cnt <= 64) {
        // softmax fully in registers: one edge per lane
        int sj = 0;                 // lanes >= cnt keep sj=0 (harmless row 0)
        float e = -3.0e38f;
        if (lane < cnt) {
            sj = srcs[s0 + lane];
            e = leaky(es[sj] + edi);
        }
        float m = e;
#pragma unroll
        for (int o = 32; o; o >>= 1) m = fmaxf(m, __shfl_xor(m, o));
        float w = (lane < cnt) ? __expf(e - m) : 0.f;   // ==0 masks tail overhang
        z = w;
#pragma unroll
        for (int o = 32; o; o >>= 1) z += __shfl_xor(z, o);
        // main: 8 edges per step (4 per half), all indices < cnt <= 64
        int jb = 0;
        for (; jb + 8 <= cnt; jb += 8) {
            int j0 = jb + half, j1 = jb + 2 + half, j2 = jb + 4 + half, j3 = jb + 6 + half;
            int   sa = __shfl(sj, j0), sb = __shfl(sj, j1);
            int   sc = __shfl(sj, j2), sd = __shfl(sj, j3);
            float wa = __shfl(w, j0),  wb = __shfl(w, j1);
            float wc = __shfl(w, j2),  wd = __shfl(w, j3);
            float4 ga = *(const float4*)(g + (size_t)sa * 128 + l32 * 4);
            float4 gb = *(const float4*)(g + (size_t)sb * 128 + l32 * 4);
            float4 gc = *(const float4*)(g + (size_t)sc * 128 + l32 * 4);
            float4 gd = *(const float4*)(g + (size_t)sd * 128 + l32 * 4);
            acc.x += wa * ga.x + wb * gb.x + wc * gc.x + wd * gd.x;
            acc.y += wa * ga.y + wb * gb.y + wc * gc.y + wd * gd.y;
            acc.z += wa * ga.z + wb * gb.z + wc * gc.z + wd * gd.z;
            acc.w += wa * ga.w + wb * gb.w + wc * gc.w + wd * gd.w;
        }
        // tail: 2 edges per step; j = jb+half <= 63 always (jb even, jb < cnt),
        // and for j >= cnt the shfl'd w is 0 -> contributes nothing.
        for (; jb < cnt; jb += 2) {
            int j = jb + half;
            int   sa = __shfl(sj, j);
            float wa = __shfl(w, j);
            float4 ga = *(const float4*)(g + (size_t)sa * 128 + l32 * 4);
            acc.x += wa * ga.x; acc.y += wa * ga.y;
            acc.z += wa * ga.z; acc.w += wa * ga.w;
        }
    } else {
        // generic path (deg > 64, rare) — no shfl inside divergent region
        float m = -3.0e38f;
        for (int jj = s0 + lane; jj < s1; jj += 64)
            m = fmaxf(m, leaky(es[srcs[jj]] + edi));
#pragma unroll
        for (int o = 32; o; o >>= 1) m = fmaxf(m, __shfl_xor(m, o));
        for (int j = s0 + half; j < s1; j += 2) {
            int s = srcs[j];
            float wj = __expf(leaky(es[s] + edi) - m);
            z += wj;
            float4 gv = *(const float4*)(g + (size_t)s * 128 + l32 * 4);
            acc.x += wj * gv.x; acc.y += wj * gv.y;
            acc.z += wj * gv.z; acc.w += wj * gv.w;
        }
        z += __shfl_xor(z, 32);
    }
    // combine the two half-wave partials (same cols l32*4..+3)
    acc.x += __shfl_xor(acc.x, 32);
    acc.y += __shfl_xor(acc.y, 32);
    acc.z += __shfl_xor(acc.z, 32);
    acc.w += __shfl_xor(acc.w, 32);
    if (half == 0) {
        float pv = p[0];
        float inv = 1.f / z;
        float4 bb = *(const float4*)(b + l32 * 4);
        float o0 = acc.x * inv + bb.x;
        float o1 = acc.y * inv + bb.y;
        float o2 = acc.z * inv + bb.z;
        float o3 = acc.w * inv + bb.w;
        o0 = (o0 >= 0.f) ? o0 : pv * o0;
        o1 = (o1 >= 0.f) ? o1 : pv * o1;
        o2 = (o2 >= 0.f) ? o2 : pv * o2;
        o3 = (o3 >= 0.f) ? o3 : pv * o3;
        *(float4*)(hout + (size_t)i * 128 + l32 * 4) = make_float4(o0, o1, o2, o3);
    }
}

extern "C" void kernel_launch(void* const* d_in, const int* in_sizes, int n_in,
                              void* d_out, int out_size, void* d_ws, size_t ws_size,
                              hipStream_t stream) {
    const int*   x   = (const int*)d_in[0];
    const int*   ei  = (const int*)d_in[1];
    // d_in[2] = edge_weight: unused by the reference
    const float* emb = (const float*)d_in[3];
    const float* W1  = (const float*)d_in[4];
    const float* as1 = (const float*)d_in[5];
    const float* ad1 = (const float*)d_in[6];
    const float* b1  = (const float*)d_in[7];
    const float* p1  = (const float*)d_in[8];
    const float* W2  = (const float*)d_in[9];
    const float* as2 = (const float*)d_in[10];
    const float* ad2 = (const float*)d_in[11];
    const float* b2  = (const float*)d_in[12];
    const float* p2  = (const float*)d_in[13];
    const float* W3  = (const float*)d_in[14];
    const float* as3 = (const float*)d_in[15];
    const float* ad3 = (const float*)d_in[16];
    const float* b3  = (const float*)d_in[17];
    const float* p3  = (const float*)d_in[18];
    const float* Wo  = (const float*)d_in[19];
    const float* bo  = (const float*)d_in[20];

    const int N = in_sizes[0];
    const int E = in_sizes[2];  // edge_weight length

    // workspace carve (256B aligned)
    char* wp = (char*)d_ws;
    auto carve = [&](size_t bytes) {
        char* r = wp;
        wp += (bytes + 255) & ~(size_t)255;
        return r;
    };
    float* h0     = (float*)carve((size_t)N * 128 * 4);
    float* h1     = (float*)carve((size_t)N * 128 * 4);
    float* g      = (float*)carve((size_t)N * 128 * 4);
    float* es     = (float*)carve((size_t)N * 4);
    float* ed     = (float*)carve((size_t)N * 4);
    int*   deg    = (int*)carve((size_t)N * 4);
    int*   off    = (int*)carve((size_t)(N + 1) * 4);
    int*   cursor = (int*)carve((size_t)N * 4);
    int*   srcs   = (int*)carve((size_t)(E + N) * 4);
    int*   bsum   = (int*)carve(1024 * 4);
    (void)ws_size; (void)n_in;

    // CSR build (once; reused by all 3 layers)
    deg_init_kernel<<<(N + 255) / 256, 256, 0, stream>>>(deg, N);
    hist_kernel<<<(E + 255) / 256, 256, 0, stream>>>(ei, deg, E);
    int nblk = (N + 1023) / 1024;
    scan1_kernel<<<nblk, 256, 0, stream>>>(deg, off, bsum, N);
    scan2_kernel<<<1, 256, 0, stream>>>(bsum, nblk);
    scan3_kernel<<<nblk, 256, 0, stream>>>(off, cursor, bsum, N, E);
    fill_kernel<<<(E + N + 255) / 256, 256, 0, stream>>>(ei, cursor, srcs, E, N);

    int gemm_grid = (N + 63) / 64;
    int wave_grid = (N * 64 + 255) / 256;

    // layer 1: emb[x] -> h1   (gather fused into GEMM A-load via rowidx=x)
    gemm128_kernel<<<gemm_grid, 256, 0, stream>>>(emb, x, W1, nullptr, as1, ad1, g, es, ed, N);
    aggregate_kernel<<<wave_grid, 256, 0, stream>>>(g, es, ed, off, srcs, b1, p1, h1, N);
    // layer 2: h1 -> h0
    gemm128_kernel<<<gemm_grid, 256, 0, stream>>>(h1, nullptr, W2, nullptr, as2, ad2, g, es, ed, N);
    aggregate_kernel<<<wave_grid, 256, 0, stream>>>(g, es, ed, off, srcs, b2, p2, h0, N);
    // layer 3: h0 -> h1
    gemm128_kernel<<<gemm_grid, 256, 0, stream>>>(h0, nullptr, W3, nullptr, as3, ad3, g, es, ed, N);
    aggregate_kernel<<<wave_grid, 256, 0, stream>>>(g, es, ed, off, srcs, b3, p3, h1, N);
    // output projection
    gemm128_kernel<<<gemm_grid, 256, 0, stream>>>(h1, nullptr, Wo, bo, nullptr, nullptr,
                                                  (float*)d_out, nullptr, nullptr, N);
}